// Round 2
// 1778.003 us; speedup vs baseline: 1.0994x; 1.0994x over previous
//
#include <hip/hip_runtime.h>
#include <hip/hip_bf16.h>

#define N_NODES 40960
#define N_SESS  4096
#define N_EDGES 81920
#define DIM     64
#define HID     100
#define VITEMS  50000

typedef short s16x8 __attribute__((ext_vector_type(8)));   // 8 bf16 (4 VGPRs)
typedef float f32x4 __attribute__((ext_vector_type(4)));   // MFMA accumulator

__device__ __forceinline__ unsigned short f2bf(float f) {  // fp32 -> bf16 RNE
    unsigned u = __float_as_uint(f);
    return (unsigned short)((u + 0x7FFFu + ((u >> 16) & 1u)) >> 16);
}
__device__ __forceinline__ float bf2f(unsigned short s) {
    return __uint_as_float(((unsigned)s) << 16);
}

// ---------------------------------------------------------------------------
// Generic fp32 tiled GEMM: C[M,N] = A[M,K] @ B[K,N] (+bias) (optional relu)
// ---------------------------------------------------------------------------
__global__ __launch_bounds__(256)
void gemm_f32(const float* __restrict__ A, int lda,
              const float* __restrict__ B, int ldb,
              const float* __restrict__ bias,
              float* __restrict__ C, int ldc,
              int M, int N, int K, int relu)
{
    __shared__ float As[32][68];
    __shared__ float Bs[32][68];
    const int tid = threadIdx.x;
    const int tm = tid & 15;
    const int tn = tid >> 4;
    const int m0 = blockIdx.y * 64;
    const int n0 = blockIdx.x * 64;
    float acc[4][4] = {};

    for (int k0 = 0; k0 < K; k0 += 32) {
        #pragma unroll
        for (int i = 0; i < 2; ++i) {
            int f4  = tid + i * 256;
            int row = f4 >> 3;
            int kc  = (f4 & 7) << 2;
            float4 v = make_float4(0.f, 0.f, 0.f, 0.f);
            int gm = m0 + row, gk = k0 + kc;
            if (gm < M && gk < K)
                v = *reinterpret_cast<const float4*>(&A[(size_t)gm * lda + gk]);
            As[kc + 0][row] = v.x;
            As[kc + 1][row] = v.y;
            As[kc + 2][row] = v.z;
            As[kc + 3][row] = v.w;
        }
        #pragma unroll
        for (int i = 0; i < 2; ++i) {
            int f4  = tid + i * 256;
            int row = f4 >> 4;
            int nc  = (f4 & 15) << 2;
            float4 v = make_float4(0.f, 0.f, 0.f, 0.f);
            int gk = k0 + row, gn = n0 + nc;
            if (gk < K && gn < N)
                v = *reinterpret_cast<const float4*>(&B[(size_t)gk * ldb + gn]);
            *reinterpret_cast<float4*>(&Bs[row][nc]) = v;
        }
        __syncthreads();
        #pragma unroll
        for (int kk = 0; kk < 32; ++kk) {
            float4 a4 = *reinterpret_cast<const float4*>(&As[kk][tm << 2]);
            float4 b4 = *reinterpret_cast<const float4*>(&Bs[kk][tn << 2]);
            float av[4] = {a4.x, a4.y, a4.z, a4.w};
            float bv[4] = {b4.x, b4.y, b4.z, b4.w};
            #pragma unroll
            for (int i = 0; i < 4; ++i)
                #pragma unroll
                for (int j = 0; j < 4; ++j)
                    acc[i][j] += av[i] * bv[j];
        }
        __syncthreads();
    }

    const int gn0 = n0 + (tn << 2);
    if (gn0 >= N) return;
    float4 bi = make_float4(0.f, 0.f, 0.f, 0.f);
    if (bias) bi = *reinterpret_cast<const float4*>(&bias[gn0]);
    #pragma unroll
    for (int i = 0; i < 4; ++i) {
        int gm = m0 + (tm << 2) + i;
        if (gm >= M) continue;
        float4 o = make_float4(acc[i][0] + bi.x, acc[i][1] + bi.y,
                               acc[i][2] + bi.z, acc[i][3] + bi.w);
        if (relu) {
            o.x = fmaxf(o.x, 0.f); o.y = fmaxf(o.y, 0.f);
            o.z = fmaxf(o.z, 0.f); o.w = fmaxf(o.w, 0.f);
        }
        *reinterpret_cast<float4*>(&C[(size_t)gm * ldc + gn0]) = o;
    }
}

// ---------------------------------------------------------------------------
// W_fc [100][50000] fp32 -> Bh/Bl [50048][128] bf16 (transposed, K-padded,
// n-padded with zeros). LDS transpose so both global read & write coalesce.
// ---------------------------------------------------------------------------
__global__ __launch_bounds__(256)
void b_split(const float* __restrict__ Wfc, unsigned short* __restrict__ Bh,
             unsigned short* __restrict__ Bl)
{
    __shared__ unsigned short Hs[64][136];   // 136: rows stay 16B-aligned
    __shared__ unsigned short Ls[64][136];
    const int n0 = blockIdx.x * 64;
    const int nn = threadIdx.x & 63, kk = threadIdx.x >> 6;  // kk 0..3
    for (int k = kk; k < 128; k += 4) {
        float v = 0.f;
        int n = n0 + nn;
        if (k < HID && n < VITEMS) v = Wfc[(size_t)k * VITEMS + n];
        unsigned short h = f2bf(v);
        Hs[nn][k] = h;
        Ls[nn][k] = f2bf(v - bf2f(h));
    }
    __syncthreads();
    const int row = threadIdx.x >> 2, part = threadIdx.x & 3;  // 4 thr/row, 64B each
    size_t base = (size_t)(n0 + row) * 128 + part * 32;
    #pragma unroll
    for (int c = 0; c < 4; ++c) {
        *reinterpret_cast<s16x8*>(&Bh[base + c * 8]) =
            *reinterpret_cast<const s16x8*>(&Hs[row][part * 32 + c * 8]);
        *reinterpret_cast<s16x8*>(&Bl[base + c * 8]) =
            *reinterpret_cast<const s16x8*>(&Ls[row][part * 32 + c * 8]);
    }
}

// pooled [4096][100] fp32 -> Ah/Al [4096][128] bf16 (K-padded)
__global__ void a_split(const float* __restrict__ pooled, unsigned short* __restrict__ Ah,
                        unsigned short* __restrict__ Al)
{
    int idx = blockIdx.x * 256 + threadIdx.x;
    if (idx >= N_SESS * 128) return;
    int m = idx >> 7, k = idx & 127;
    float v = (k < HID) ? pooled[m * HID + k] : 0.f;
    unsigned short h = f2bf(v);
    Ah[idx] = h;
    Al[idx] = f2bf(v - bf2f(h));
}

// ---------------------------------------------------------------------------
// out[4096,50000] = A @ B + bias via bf16 hi/lo MFMA (AhBh + AlBh + AhBl).
// grid 512: chunk = blk&7 (XCD-affine N-chunk, keeps 3.2MB B slice in L2),
// mtile = blk>>3. A-frags for 64 rows live in registers across the N loop.
// Each wave owns 16 of the 64 tile columns. No LDS, no barriers.
// ---------------------------------------------------------------------------
__global__ __launch_bounds__(256)
void score_gemm(const unsigned short* __restrict__ Ah, const unsigned short* __restrict__ Al,
                const unsigned short* __restrict__ Bh, const unsigned short* __restrict__ Bl,
                const float* __restrict__ bias, float* __restrict__ out)
{
    const int chunk = blockIdx.x & 7;
    const int m0    = (blockIdx.x >> 3) * 64;
    const int w     = threadIdx.x >> 6;   // wave 0..3
    const int l     = threadIdx.x & 63;
    const int lm    = l & 15;             // row/col within fragment
    const int lk    = l >> 4;             // k-group (8 contiguous k each)

    s16x8 ah[4][4], al[4][4];             // [m-frag][k-step] : 128 VGPRs, loop-invariant
    #pragma unroll
    for (int mf = 0; mf < 4; ++mf)
        #pragma unroll
        for (int ks = 0; ks < 4; ++ks) {
            size_t off = (size_t)(m0 + mf * 16 + lm) * 128 + ks * 32 + lk * 8;
            ah[mf][ks] = *reinterpret_cast<const s16x8*>(Ah + off);
            al[mf][ks] = *reinterpret_cast<const s16x8*>(Al + off);
        }

    const int t0 = chunk * 98;
    const int t1 = (t0 + 98 < 782) ? t0 + 98 : 782;
    for (int nt = t0; nt < t1; ++nt) {
        const int n0 = nt * 64 + w * 16;
        f32x4 acc[4];
        #pragma unroll
        for (int mf = 0; mf < 4; ++mf) acc[mf] = (f32x4){0.f, 0.f, 0.f, 0.f};

        #pragma unroll
        for (int ks = 0; ks < 4; ++ks) {
            size_t boff = (size_t)(n0 + lm) * 128 + ks * 32 + lk * 8;
            s16x8 bh = *reinterpret_cast<const s16x8*>(Bh + boff);
            s16x8 bl = *reinterpret_cast<const s16x8*>(Bl + boff);
            #pragma unroll
            for (int mf = 0; mf < 4; ++mf) {
                acc[mf] = __builtin_amdgcn_mfma_f32_16x16x32_bf16(ah[mf][ks], bh, acc[mf], 0, 0, 0);
                acc[mf] = __builtin_amdgcn_mfma_f32_16x16x32_bf16(al[mf][ks], bh, acc[mf], 0, 0, 0);
                acc[mf] = __builtin_amdgcn_mfma_f32_16x16x32_bf16(ah[mf][ks], bl, acc[mf], 0, 0, 0);
            }
        }

        const int n = n0 + lm;
        if (n < VITEMS) {
            const float bv = bias[n];
            #pragma unroll
            for (int mf = 0; mf < 4; ++mf) {
                const int mbase = m0 + mf * 16 + lk * 4;   // C/D: col=lane&15, row=(lane>>4)*4+reg
                #pragma unroll
                for (int r = 0; r < 4; ++r)
                    out[(size_t)(mbase + r) * VITEMS + n] = acc[mf][r] + bv;
            }
        }
    }
}

// h0[n,j] = b_msg[j] + price[n]*W_msg[0,j] + sum of 5 projected-table gathers
__global__ void h0_gather(const float* __restrict__ price,
                          const int* __restrict__ cat, const int* __restrict__ sub,
                          const int* __restrict__ elem, const int* __restrict__ brand,
                          const int* __restrict__ pid,
                          const float* __restrict__ Wmsg, const float* __restrict__ b_msg,
                          const float* __restrict__ Pm, float* __restrict__ h0)
{
    int idx = blockIdx.x * 256 + threadIdx.x;
    if (idx >= N_NODES * HID) return;
    int n = idx / HID, j = idx - n * HID;
    float v = b_msg[j] + price[n] * Wmsg[j];
    v += Pm[(size_t)(        cat[n]) * HID + j];
    v += Pm[(size_t)( 256 +  sub[n]) * HID + j];
    v += Pm[(size_t)(1280 + elem[n]) * HID + j];
    v += Pm[(size_t)(3328 + brand[n]) * HID + j];
    v += Pm[(size_t)(7424 +  pid[n]) * HID + j];
    h0[idx] = v;
}

__global__ void deg_count(const int* __restrict__ dst, float* __restrict__ deg)
{
    int e = blockIdx.x * 256 + threadIdx.x;
    if (e < N_EDGES) atomicAdd(&deg[dst[e]], 1.0f);
}

__global__ void inv_deg_k(float* __restrict__ deg)
{
    int n = blockIdx.x * 256 + threadIdx.x;
    if (n < N_NODES) {
        float d = deg[n];
        deg[n] = d > 0.f ? 1.0f / d : 0.0f;
    }
}

__global__ void msg_scatter(const int* __restrict__ src, const int* __restrict__ dst,
                            const float* __restrict__ h0, float* __restrict__ msg)
{
    int idx = blockIdx.x * 256 + threadIdx.x;
    if (idx >= N_EDGES * HID) return;
    int e = idx / HID, j = idx - e * HID;
    atomicAdd(&msg[(size_t)dst[e] * HID + j], h0[(size_t)src[e] * HID + j]);
}

__global__ void msg_scale(const float* __restrict__ inv_deg, float* __restrict__ msg)
{
    int idx = blockIdx.x * 256 + threadIdx.x;
    if (idx >= N_NODES * HID) return;
    int n = idx / HID;
    msg[idx] *= inv_deg[n];
}

__global__ void gru_gates(const float* __restrict__ gi, const float* __restrict__ gh,
                          float* __restrict__ h)
{
    int idx = blockIdx.x * 256 + threadIdx.x;
    if (idx >= 10240 * HID) return;
    int nl = idx / HID, j = idx - nl * HID;
    float ir  = gi[nl * 300 + j],        hr = gh[nl * 300 + j];
    float iz  = gi[nl * 300 + 100 + j],  hz = gh[nl * 300 + 100 + j];
    float in_ = gi[nl * 300 + 200 + j],  hn = gh[nl * 300 + 200 + j];
    float r  = 1.f / (1.f + expf(-(ir + hr)));
    float z  = 1.f / (1.f + expf(-(iz + hz)));
    float nn = tanhf(in_ + r * hn);
    float hv = h[idx];
    h[idx] = (1.f - z) * nn + z * hv;
}

__global__ void last_idx_k(const int* __restrict__ batch, int* __restrict__ last_idx)
{
    int n = blockIdx.x * 256 + threadIdx.x;
    if (n < N_NODES) atomicMax(&last_idx[batch[n]], n);
}

__global__ __launch_bounds__(256)
void last_proj(const int* __restrict__ last_idx, const float* __restrict__ price,
               const int* __restrict__ cat, const int* __restrict__ sub,
               const int* __restrict__ elem, const int* __restrict__ brand,
               const int* __restrict__ pid,
               const float* __restrict__ Ecat, const float* __restrict__ Esub,
               const float* __restrict__ Eelem, const float* __restrict__ Ebrand,
               const float* __restrict__ Eitem,
               const float* __restrict__ W_last, const float* __restrict__ b_last,
               float* __restrict__ last)
{
    int s = blockIdx.x * 4 + (threadIdx.x >> 6);
    int l = threadIdx.x & 63;
    int n = last_idx[s];
    int ci = cat[n] * DIM, si = sub[n] * DIM, ei = elem[n] * DIM;
    int bi = brand[n] * DIM, pi = pid[n] * DIM;
    float acc0 = 0.f, acc1 = 0.f;
    for (int k = 0; k < 321; ++k) {
        float xk;
        if (k == 0)       xk = price[n];
        else if (k < 65)  xk = Ecat[ci + k - 1];
        else if (k < 129) xk = Esub[si + k - 65];
        else if (k < 193) xk = Eelem[ei + k - 129];
        else if (k < 257) xk = Ebrand[bi + k - 193];
        else              xk = Eitem[pi + k - 257];
        acc0 += xk * W_last[k * HID + l];
        if (l < HID - 64) acc1 += xk * W_last[k * HID + 64 + l];
    }
    last[s * HID + l] = acc0 + b_last[l];
    if (l < HID - 64) last[s * HID + 64 + l] = acc1 + b_last[64 + l];
}

__global__ void add_last(const int* __restrict__ batch, const float* __restrict__ last,
                         float* __restrict__ h)
{
    int idx = blockIdx.x * 256 + threadIdx.x;
    if (idx >= N_NODES * HID) return;
    int n = idx / HID, j = idx - n * HID;
    h[idx] += last[(size_t)batch[n] * HID + j];
}

__global__ __launch_bounds__(256)
void gate_reduce(const float* __restrict__ g1, const float* __restrict__ W_g2,
                 const float* __restrict__ b_g2, const int* __restrict__ batch,
                 float* __restrict__ gate, unsigned* __restrict__ gmax)
{
    int n = blockIdx.x * 4 + (threadIdx.x >> 6);
    int l = threadIdx.x & 63;
    float s = g1[(size_t)n * HID + l] * W_g2[l];
    if (l < HID - 64) s += g1[(size_t)n * HID + 64 + l] * W_g2[64 + l];
    #pragma unroll
    for (int off = 32; off > 0; off >>= 1) s += __shfl_xor(s, off, 64);
    if (l == 0) {
        float gt = s + b_g2[0];
        gate[n] = gt;
        unsigned u = __float_as_uint(gt);
        u = (u & 0x80000000u) ? ~u : (u | 0x80000000u);
        atomicMax(&gmax[batch[n]], u);
    }
}

__global__ void softmax_w(const int* __restrict__ batch, const unsigned* __restrict__ gmax,
                          float* __restrict__ gate, float* __restrict__ wsum)
{
    int n = blockIdx.x * 256 + threadIdx.x;
    if (n >= N_NODES) return;
    unsigned u = gmax[batch[n]];
    float gm = (u & 0x80000000u) ? __uint_as_float(u ^ 0x80000000u) : __uint_as_float(~u);
    float w = expf(gate[n] - gm);
    gate[n] = w;
    atomicAdd(&wsum[batch[n]], w);
}

__global__ void pooled_k(const int* __restrict__ batch, const float* __restrict__ gate,
                         const float* __restrict__ wsum, const float* __restrict__ h,
                         float* __restrict__ pooled)
{
    int idx = blockIdx.x * 256 + threadIdx.x;
    if (idx >= N_NODES * HID) return;
    int n = idx / HID, j = idx - n * HID;
    int b = batch[n];
    float alpha = gate[n] / wsum[b];
    atomicAdd(&pooled[(size_t)b * HID + j], alpha * h[idx]);
}

extern "C" void kernel_launch(void* const* d_in, const int* in_sizes, int n_in,
                              void* d_out, int out_size, void* d_ws, size_t ws_size,
                              hipStream_t stream)
{
    const float* price    = (const float*)d_in[0];
    const int*   cat      = (const int*)d_in[1];
    const int*   sub      = (const int*)d_in[2];
    const int*   elem     = (const int*)d_in[3];
    const int*   brand    = (const int*)d_in[4];
    const int*   pid      = (const int*)d_in[5];
    const int*   eidx     = (const int*)d_in[6];
    const int*   batch    = (const int*)d_in[7];
    const float* emb_cat  = (const float*)d_in[8];
    const float* emb_sub  = (const float*)d_in[9];
    const float* emb_elem = (const float*)d_in[10];
    const float* emb_brand= (const float*)d_in[11];
    const float* emb_item = (const float*)d_in[12];
    const float* W_msg    = (const float*)d_in[13];
    const float* b_msg    = (const float*)d_in[14];
    const float* W_ih     = (const float*)d_in[15];
    const float* W_hh     = (const float*)d_in[16];
    const float* b_ih     = (const float*)d_in[17];
    const float* b_hh     = (const float*)d_in[18];
    const float* W_last   = (const float*)d_in[19];
    const float* b_last   = (const float*)d_in[20];
    const float* W_g1     = (const float*)d_in[21];
    const float* b_g1     = (const float*)d_in[22];
    const float* W_g2     = (const float*)d_in[23];
    const float* b_g2     = (const float*)d_in[24];
    const float* W_fc     = (const float*)d_in[25];
    const float* b_fc     = (const float*)d_in[26];
    float* out = (float*)d_out;

    const int* src = eidx;
    const int* dst = eidx + N_EDGES;

    // ---- workspace layout (float offsets); zeroed region first ----
    float* w = (float*)d_ws;
    float*    msg    = w + 0;          // N*HID        = 4096000
    float*    deg    = w + 4096000;    // N            = 40960
    float*    wsum   = w + 4136960;    // S            = 4096
    float*    pooled = w + 4141056;    // S*HID        = 409600
    int*      lastix = (int*)(w + 4550656);      // S  = 4096
    unsigned* gmax   = (unsigned*)(w + 4554752); // S  = 4096
    // zero region total: 4558848 floats
    float*    Pm     = w + 4558848;    // 57424*HID    = 5742400
    float*    h0     = w + 10301248;   // N*HID        = 4096000
    float*    gi     = w + 14397248;   // 10240*300    = 3072000
    float*    gh     = w + 17469248;   // 10240*300    = 3072000
    float*    last   = w + 20541248;   // S*HID        = 409600
    float*    gate   = w + 20950848;   // N            = 40960
    // total: 20991808 floats = ~84 MB

    // bf16 hi/lo tables reuse freed regions:
    //  Bth -> msg region   (needs 3203072 floats < 4096000; msg dead after gate_reduce)
    //  Btl -> gi region    (needs 3203072 floats < gi+gh 6144000; dead after GRU)
    //  Ah/Al -> Pm region  (needs 2*262144 floats; Pm dead after h0_gather)
    unsigned short* Bth = (unsigned short*)msg;
    unsigned short* Btl = (unsigned short*)gi;
    unsigned short* Ahp = (unsigned short*)Pm;
    unsigned short* Alp = (unsigned short*)(Pm + 262144);

    hipMemsetAsync(w, 0, (size_t)4558848 * sizeof(float), stream);

    dim3 blk(256);
    auto gemm = [&](const float* A, int lda, const float* B, int ldb,
                    const float* bias, float* C, int ldc, int M, int N, int K, int relu) {
        dim3 g((N + 63) / 64, (M + 63) / 64);
        hipLaunchKernelGGL(gemm_f32, g, blk, 0, stream, A, lda, B, ldb, bias, C, ldc, M, N, K, relu);
    };

    // ---- projected embedding tables for W_msg (row 0 = price handled in gather) ----
    gemm(emb_cat,   DIM, W_msg +   1 * HID, HID, nullptr, Pm +      0, HID,   256, HID, DIM, 0);
    gemm(emb_sub,   DIM, W_msg +  65 * HID, HID, nullptr, Pm +  25600, HID,  1024, HID, DIM, 0);
    gemm(emb_elem,  DIM, W_msg + 129 * HID, HID, nullptr, Pm + 128000, HID,  2048, HID, DIM, 0);
    gemm(emb_brand, DIM, W_msg + 193 * HID, HID, nullptr, Pm + 332800, HID,  4096, HID, DIM, 0);
    gemm(emb_item,  DIM, W_msg + 257 * HID, HID, nullptr, Pm + 742400, HID, VITEMS, HID, DIM, 0);

    // ---- h0 = x @ W_msg + b_msg via gathers ----
    h0_gather<<<16000, blk, 0, stream>>>(price, cat, sub, elem, brand, pid, W_msg, b_msg, Pm, h0);

    // ---- degree + mean aggregation ----
    deg_count<<<320, blk, 0, stream>>>(dst, deg);
    inv_deg_k<<<160, blk, 0, stream>>>(deg);
    msg_scatter<<<32000, blk, 0, stream>>>(src, dst, h0, msg);
    msg_scale<<<16000, blk, 0, stream>>>(deg, msg);

    // ---- GRU cell, 4 chunks of 10240 nodes ----
    for (int c = 0; c < 4; ++c) {
        size_t nb = (size_t)c * 10240;
        gemm(msg + nb * HID, HID, W_ih, 300, b_ih, gi, 300, 10240, 300, HID, 0);
        gemm(h0  + nb * HID, HID, W_hh, 300, b_hh, gh, 300, 10240, 300, HID, 0);
        gru_gates<<<4000, blk, 0, stream>>>(gi, gh, h0 + nb * HID);
    }

    // ---- last-node projection and broadcast add ----
    last_idx_k<<<160, blk, 0, stream>>>(batch, lastix);
    last_proj<<<1024, blk, 0, stream>>>(lastix, price, cat, sub, elem, brand, pid,
                                        emb_cat, emb_sub, emb_elem, emb_brand, emb_item,
                                        W_last, b_last, last);
    add_last<<<16000, blk, 0, stream>>>(batch, last, h0);

    // ---- attentional aggregation ----
    gemm(h0, HID, W_g1, HID, b_g1, msg /*reuse as gate1*/, HID, N_NODES, HID, HID, 1);
    gate_reduce<<<10240, blk, 0, stream>>>(msg, W_g2, b_g2, batch, gate, gmax);

    // msg (gate1) is dead now -> build W_fc bf16 hi/lo tables in its place
    b_split<<<782, blk, 0, stream>>>(W_fc, Bth, Btl);

    softmax_w<<<160, blk, 0, stream>>>(batch, gmax, gate, wsum);
    pooled_k<<<16000, blk, 0, stream>>>(batch, gate, wsum, h0, pooled);

    // ---- final scoring: bf16x3 MFMA GEMM ----
    a_split<<<2048, blk, 0, stream>>>(pooled, Ahp, Alp);
    score_gemm<<<512, blk, 0, stream>>>(Ahp, Alp, Bth, Btl, b_fc, out);
}

// Round 3
// 1614.927 us; speedup vs baseline: 1.2104x; 1.1010x over previous
//
#include <hip/hip_runtime.h>
#include <hip/hip_bf16.h>

#define N_NODES 40960
#define N_SESS  4096
#define N_EDGES 81920
#define DIM     64
#define HID     100
#define VITEMS  50000

typedef short s16x8 __attribute__((ext_vector_type(8)));   // 8 bf16 (4 VGPRs)
typedef float f32x4 __attribute__((ext_vector_type(4)));   // MFMA accumulator

__device__ __forceinline__ unsigned short f2bf(float f) {  // fp32 -> bf16 RNE
    unsigned u = __float_as_uint(f);
    return (unsigned short)((u + 0x7FFFu + ((u >> 16) & 1u)) >> 16);
}
__device__ __forceinline__ float bf2f(unsigned short s) {
    return __uint_as_float(((unsigned)s) << 16);
}

// ---------------------------------------------------------------------------
// Generic fp32 tiled GEMM: C[M,N] = A[M,K] @ B[K,N] (+bias) (optional relu)
// ---------------------------------------------------------------------------
__global__ __launch_bounds__(256)
void gemm_f32(const float* __restrict__ A, int lda,
              const float* __restrict__ B, int ldb,
              const float* __restrict__ bias,
              float* __restrict__ C, int ldc,
              int M, int N, int K, int relu)
{
    __shared__ float As[32][68];
    __shared__ float Bs[32][68];
    const int tid = threadIdx.x;
    const int tm = tid & 15;
    const int tn = tid >> 4;
    const int m0 = blockIdx.y * 64;
    const int n0 = blockIdx.x * 64;
    float acc[4][4] = {};

    for (int k0 = 0; k0 < K; k0 += 32) {
        #pragma unroll
        for (int i = 0; i < 2; ++i) {
            int f4  = tid + i * 256;
            int row = f4 >> 3;
            int kc  = (f4 & 7) << 2;
            float4 v = make_float4(0.f, 0.f, 0.f, 0.f);
            int gm = m0 + row, gk = k0 + kc;
            if (gm < M && gk < K)
                v = *reinterpret_cast<const float4*>(&A[(size_t)gm * lda + gk]);
            As[kc + 0][row] = v.x;
            As[kc + 1][row] = v.y;
            As[kc + 2][row] = v.z;
            As[kc + 3][row] = v.w;
        }
        #pragma unroll
        for (int i = 0; i < 2; ++i) {
            int f4  = tid + i * 256;
            int row = f4 >> 4;
            int nc  = (f4 & 15) << 2;
            float4 v = make_float4(0.f, 0.f, 0.f, 0.f);
            int gk = k0 + row, gn = n0 + nc;
            if (gk < K && gn < N)
                v = *reinterpret_cast<const float4*>(&B[(size_t)gk * ldb + gn]);
            *reinterpret_cast<float4*>(&Bs[row][nc]) = v;
        }
        __syncthreads();
        #pragma unroll
        for (int kk = 0; kk < 32; ++kk) {
            float4 a4 = *reinterpret_cast<const float4*>(&As[kk][tm << 2]);
            float4 b4 = *reinterpret_cast<const float4*>(&Bs[kk][tn << 2]);
            float av[4] = {a4.x, a4.y, a4.z, a4.w};
            float bv[4] = {b4.x, b4.y, b4.z, b4.w};
            #pragma unroll
            for (int i = 0; i < 4; ++i)
                #pragma unroll
                for (int j = 0; j < 4; ++j)
                    acc[i][j] += av[i] * bv[j];
        }
        __syncthreads();
    }

    const int gn0 = n0 + (tn << 2);
    if (gn0 >= N) return;
    float4 bi = make_float4(0.f, 0.f, 0.f, 0.f);
    if (bias) bi = *reinterpret_cast<const float4*>(&bias[gn0]);
    #pragma unroll
    for (int i = 0; i < 4; ++i) {
        int gm = m0 + (tm << 2) + i;
        if (gm >= M) continue;
        float4 o = make_float4(acc[i][0] + bi.x, acc[i][1] + bi.y,
                               acc[i][2] + bi.z, acc[i][3] + bi.w);
        if (relu) {
            o.x = fmaxf(o.x, 0.f); o.y = fmaxf(o.y, 0.f);
            o.z = fmaxf(o.z, 0.f); o.w = fmaxf(o.w, 0.f);
        }
        *reinterpret_cast<float4*>(&C[(size_t)gm * ldc + gn0]) = o;
    }
}

// ---------------------------------------------------------------------------
// W_fc [100][50000] fp32 -> Bh/Bl [50048][128] bf16 (transposed, K-padded)
// ---------------------------------------------------------------------------
__global__ __launch_bounds__(256)
void b_split(const float* __restrict__ Wfc, unsigned short* __restrict__ Bh,
             unsigned short* __restrict__ Bl)
{
    __shared__ unsigned short Hs[64][136];
    __shared__ unsigned short Ls[64][136];
    const int n0 = blockIdx.x * 64;
    const int nn = threadIdx.x & 63, kk = threadIdx.x >> 6;
    for (int k = kk; k < 128; k += 4) {
        float v = 0.f;
        int n = n0 + nn;
        if (k < HID && n < VITEMS) v = Wfc[(size_t)k * VITEMS + n];
        unsigned short h = f2bf(v);
        Hs[nn][k] = h;
        Ls[nn][k] = f2bf(v - bf2f(h));
    }
    __syncthreads();
    const int row = threadIdx.x >> 2, part = threadIdx.x & 3;
    size_t base = (size_t)(n0 + row) * 128 + part * 32;
    #pragma unroll
    for (int c = 0; c < 4; ++c) {
        *reinterpret_cast<s16x8*>(&Bh[base + c * 8]) =
            *reinterpret_cast<const s16x8*>(&Hs[row][part * 32 + c * 8]);
        *reinterpret_cast<s16x8*>(&Bl[base + c * 8]) =
            *reinterpret_cast<const s16x8*>(&Ls[row][part * 32 + c * 8]);
    }
}

// generic: in [M][100] fp32 -> H/L [M][128] bf16 hi/lo (K-padded with zeros)
__global__ void split_pad128(const float* __restrict__ in, int M,
                             unsigned short* __restrict__ H, unsigned short* __restrict__ L)
{
    int idx = blockIdx.x * 256 + threadIdx.x;
    if (idx >= M * 128) return;
    int m = idx >> 7, k = idx & 127;
    float v = (k < HID) ? in[(size_t)m * HID + k] : 0.f;
    unsigned short h = f2bf(v);
    H[idx] = h;
    L[idx] = f2bf(v - bf2f(h));
}

// W_ih/W_hh [100][300] fp32 -> T: [mat][hi/lo][304][128] bf16 (transposed, padded)
__global__ void wtab_split(const float* __restrict__ Wih, const float* __restrict__ Whh,
                           unsigned short* __restrict__ T)
{
    int idx = blockIdx.x * 256 + threadIdx.x;
    if (idx >= 2 * 304 * 128) return;
    int mat = idx / 38912;
    int rem = idx - mat * 38912;
    int n = rem >> 7, k = rem & 127;
    const float* W = mat ? Whh : Wih;
    float v = (k < HID && n < 300) ? W[(size_t)k * 300 + n] : 0.f;
    unsigned short h = f2bf(v);
    T[(size_t)(mat * 2) * 38912 + rem]     = h;
    T[(size_t)(mat * 2 + 1) * 38912 + rem] = f2bf(v - bf2f(h));
}

// ---------------------------------------------------------------------------
// Fused GRU: 32 nodes/block. Waves 0-1: gi = msg@W_ih (16 nodes each);
// waves 2-3: gh = h0@W_hh. bf16x3 MFMA into LDS, then gate math updates h.
// ---------------------------------------------------------------------------
__global__ __launch_bounds__(256)
void gru_fused(const unsigned short* __restrict__ MsgH, const unsigned short* __restrict__ MsgL,
               const unsigned short* __restrict__ H0H,  const unsigned short* __restrict__ H0L,
               const unsigned short* __restrict__ Wtab,
               const float* __restrict__ b_ih, const float* __restrict__ b_hh,
               float* __restrict__ h)
{
    __shared__ float Gs[2][32][306];   // stride 306: lk-groups land on disjoint-ish banks
    const int nb = blockIdx.x * 32;
    const int w  = threadIdx.x >> 6;
    const int l  = threadIdx.x & 63;
    const int lm = l & 15, lk = l >> 4;
    const int mat = w >> 1;            // 0: msg@W_ih, 1: h0@W_hh
    const int mf  = w & 1;             // 16-node group

    const unsigned short* Ah = mat ? H0H : MsgH;
    const unsigned short* Al = mat ? H0L : MsgL;
    const unsigned short* Bh = Wtab + (size_t)(mat * 2) * 38912;
    const unsigned short* Bl = Bh + 38912;

    s16x8 ah[4], al[4];
    #pragma unroll
    for (int ks = 0; ks < 4; ++ks) {
        size_t off = (size_t)(nb + mf * 16 + lm) * 128 + ks * 32 + lk * 8;
        ah[ks] = *reinterpret_cast<const s16x8*>(Ah + off);
        al[ks] = *reinterpret_cast<const s16x8*>(Al + off);
    }

    for (int nt = 0; nt < 19; ++nt) {
        f32x4 acc = (f32x4){0.f, 0.f, 0.f, 0.f};
        #pragma unroll
        for (int ks = 0; ks < 4; ++ks) {
            size_t boff = (size_t)(nt * 16 + lm) * 128 + ks * 32 + lk * 8;
            s16x8 bh = *reinterpret_cast<const s16x8*>(Bh + boff);
            s16x8 bl = *reinterpret_cast<const s16x8*>(Bl + boff);
            acc = __builtin_amdgcn_mfma_f32_16x16x32_bf16(ah[ks], bh, acc, 0, 0, 0);
            acc = __builtin_amdgcn_mfma_f32_16x16x32_bf16(al[ks], bh, acc, 0, 0, 0);
            acc = __builtin_amdgcn_mfma_f32_16x16x32_bf16(ah[ks], bl, acc, 0, 0, 0);
        }
        #pragma unroll
        for (int r = 0; r < 4; ++r)
            Gs[mat][mf * 16 + lk * 4 + r][nt * 16 + lm] = acc[r];
    }
    __syncthreads();

    for (int idx = threadIdx.x; idx < 3200; idx += 256) {
        int node = idx / 100;
        int j = idx - node * 100;
        float ir  = Gs[0][node][j]       + b_ih[j];
        float hr  = Gs[1][node][j]       + b_hh[j];
        float iz  = Gs[0][node][100 + j] + b_ih[100 + j];
        float hz  = Gs[1][node][100 + j] + b_hh[100 + j];
        float in_ = Gs[0][node][200 + j] + b_ih[200 + j];
        float hn  = Gs[1][node][200 + j] + b_hh[200 + j];
        float r  = 1.f / (1.f + expf(-(ir + hr)));
        float z  = 1.f / (1.f + expf(-(iz + hz)));
        float nn = tanhf(in_ + r * hn);
        size_t g = (size_t)(nb + node) * HID + j;
        float hv = h[g];
        h[g] = (1.f - z) * nn + z * hv;
    }
}

// ---------------------------------------------------------------------------
// out[4096,50000] = A @ B + bias via bf16 hi/lo MFMA, 2-deep B prefetch.
// ---------------------------------------------------------------------------
__global__ __launch_bounds__(256)
void score_gemm(const unsigned short* __restrict__ Ah, const unsigned short* __restrict__ Al,
                const unsigned short* __restrict__ Bh, const unsigned short* __restrict__ Bl,
                const float* __restrict__ bias, float* __restrict__ out)
{
    const int chunk = blockIdx.x & 7;
    const int m0    = (blockIdx.x >> 3) * 64;
    const int w     = threadIdx.x >> 6;
    const int l     = threadIdx.x & 63;
    const int lm    = l & 15;
    const int lk    = l >> 4;

    s16x8 ah[4][4], al[4][4];             // loop-invariant A fragments
    #pragma unroll
    for (int mf = 0; mf < 4; ++mf)
        #pragma unroll
        for (int ks = 0; ks < 4; ++ks) {
            size_t off = (size_t)(m0 + mf * 16 + lm) * 128 + ks * 32 + lk * 8;
            ah[mf][ks] = *reinterpret_cast<const s16x8*>(Ah + off);
            al[mf][ks] = *reinterpret_cast<const s16x8*>(Al + off);
        }

    const int t0 = chunk * 98;
    const int t1 = (t0 + 98 < 782) ? t0 + 98 : 782;

    s16x8 bh[4], bl[4];
    #pragma unroll
    for (int ks = 0; ks < 4; ++ks) {
        size_t boff = (size_t)(t0 * 64 + w * 16 + lm) * 128 + ks * 32 + lk * 8;
        bh[ks] = *reinterpret_cast<const s16x8*>(Bh + boff);
        bl[ks] = *reinterpret_cast<const s16x8*>(Bl + boff);
    }

    for (int nt = t0; nt < t1; ++nt) {
        const int ntn = (nt + 1 < t1) ? nt + 1 : nt;
        s16x8 nbh[4], nbl[4];
        #pragma unroll
        for (int ks = 0; ks < 4; ++ks) {   // prefetch next tile's B fragments
            size_t boff = (size_t)(ntn * 64 + w * 16 + lm) * 128 + ks * 32 + lk * 8;
            nbh[ks] = *reinterpret_cast<const s16x8*>(Bh + boff);
            nbl[ks] = *reinterpret_cast<const s16x8*>(Bl + boff);
        }

        f32x4 acc[4];
        #pragma unroll
        for (int mf = 0; mf < 4; ++mf) acc[mf] = (f32x4){0.f, 0.f, 0.f, 0.f};

        #pragma unroll
        for (int ks = 0; ks < 4; ++ks) {
            #pragma unroll
            for (int mf = 0; mf < 4; ++mf) {
                acc[mf] = __builtin_amdgcn_mfma_f32_16x16x32_bf16(ah[mf][ks], bh[ks], acc[mf], 0, 0, 0);
                acc[mf] = __builtin_amdgcn_mfma_f32_16x16x32_bf16(al[mf][ks], bh[ks], acc[mf], 0, 0, 0);
                acc[mf] = __builtin_amdgcn_mfma_f32_16x16x32_bf16(ah[mf][ks], bl[ks], acc[mf], 0, 0, 0);
            }
        }

        const int n = nt * 64 + w * 16 + lm;
        if (n < VITEMS) {
            const float bv = bias[n];
            #pragma unroll
            for (int mf = 0; mf < 4; ++mf) {
                const int mbase = m0 + mf * 16 + lk * 4;
                #pragma unroll
                for (int r = 0; r < 4; ++r)
                    out[(size_t)(mbase + r) * VITEMS + n] = acc[mf][r] + bv;
            }
        }

        #pragma unroll
        for (int ks = 0; ks < 4; ++ks) { bh[ks] = nbh[ks]; bl[ks] = nbl[ks]; }
    }
}

// h0[n,j] = b_msg[j] + price[n]*W_msg[0,j] + sum of 5 projected-table gathers
__global__ void h0_gather(const float* __restrict__ price,
                          const int* __restrict__ cat, const int* __restrict__ sub,
                          const int* __restrict__ elem, const int* __restrict__ brand,
                          const int* __restrict__ pid,
                          const float* __restrict__ Wmsg, const float* __restrict__ b_msg,
                          const float* __restrict__ Pm, float* __restrict__ h0)
{
    int idx = blockIdx.x * 256 + threadIdx.x;
    if (idx >= N_NODES * HID) return;
    int n = idx / HID, j = idx - n * HID;
    float v = b_msg[j] + price[n] * Wmsg[j];
    v += Pm[(size_t)(        cat[n]) * HID + j];
    v += Pm[(size_t)( 256 +  sub[n]) * HID + j];
    v += Pm[(size_t)(1280 + elem[n]) * HID + j];
    v += Pm[(size_t)(3328 + brand[n]) * HID + j];
    v += Pm[(size_t)(7424 +  pid[n]) * HID + j];
    h0[idx] = v;
}

__global__ void deg_count(const int* __restrict__ dst, float* __restrict__ deg)
{
    int e = blockIdx.x * 256 + threadIdx.x;
    if (e < N_EDGES) atomicAdd(&deg[dst[e]], 1.0f);
}

__global__ void inv_deg_k(float* __restrict__ deg)
{
    int n = blockIdx.x * 256 + threadIdx.x;
    if (n < N_NODES) {
        float d = deg[n];
        deg[n] = d > 0.f ? 1.0f / d : 0.0f;
    }
}

__global__ void msg_scatter(const int* __restrict__ src, const int* __restrict__ dst,
                            const float* __restrict__ h0, float* __restrict__ msg)
{
    int idx = blockIdx.x * 256 + threadIdx.x;
    if (idx >= N_EDGES * HID) return;
    int e = idx / HID, j = idx - e * HID;
    atomicAdd(&msg[(size_t)dst[e] * HID + j], h0[(size_t)src[e] * HID + j]);
}

__global__ void msg_scale(const float* __restrict__ inv_deg, float* __restrict__ msg)
{
    int idx = blockIdx.x * 256 + threadIdx.x;
    if (idx >= N_NODES * HID) return;
    int n = idx / HID;
    msg[idx] *= inv_deg[n];
}

__global__ void last_idx_k(const int* __restrict__ batch, int* __restrict__ last_idx)
{
    int n = blockIdx.x * 256 + threadIdx.x;
    if (n < N_NODES) atomicMax(&last_idx[batch[n]], n);
}

__global__ __launch_bounds__(256)
void last_proj(const int* __restrict__ last_idx, const float* __restrict__ price,
               const int* __restrict__ cat, const int* __restrict__ sub,
               const int* __restrict__ elem, const int* __restrict__ brand,
               const int* __restrict__ pid,
               const float* __restrict__ Ecat, const float* __restrict__ Esub,
               const float* __restrict__ Eelem, const float* __restrict__ Ebrand,
               const float* __restrict__ Eitem,
               const float* __restrict__ W_last, const float* __restrict__ b_last,
               float* __restrict__ last)
{
    int s = blockIdx.x * 4 + (threadIdx.x >> 6);
    int l = threadIdx.x & 63;
    int n = last_idx[s];
    int ci = cat[n] * DIM, si = sub[n] * DIM, ei = elem[n] * DIM;
    int bi = brand[n] * DIM, pi = pid[n] * DIM;
    float acc0 = 0.f, acc1 = 0.f;
    for (int k = 0; k < 321; ++k) {
        float xk;
        if (k == 0)       xk = price[n];
        else if (k < 65)  xk = Ecat[ci + k - 1];
        else if (k < 129) xk = Esub[si + k - 65];
        else if (k < 193) xk = Eelem[ei + k - 129];
        else if (k < 257) xk = Ebrand[bi + k - 193];
        else              xk = Eitem[pi + k - 257];
        acc0 += xk * W_last[k * HID + l];
        if (l < HID - 64) acc1 += xk * W_last[k * HID + 64 + l];
    }
    last[s * HID + l] = acc0 + b_last[l];
    if (l < HID - 64) last[s * HID + 64 + l] = acc1 + b_last[64 + l];
}

__global__ void add_last(const int* __restrict__ batch, const float* __restrict__ last,
                         float* __restrict__ h)
{
    int idx = blockIdx.x * 256 + threadIdx.x;
    if (idx >= N_NODES * HID) return;
    int n = idx / HID, j = idx - n * HID;
    h[idx] += last[(size_t)batch[n] * HID + j];
}

__global__ __launch_bounds__(256)
void gate_reduce(const float* __restrict__ g1, const float* __restrict__ W_g2,
                 const float* __restrict__ b_g2, const int* __restrict__ batch,
                 float* __restrict__ gate, unsigned* __restrict__ gmax)
{
    int n = blockIdx.x * 4 + (threadIdx.x >> 6);
    int l = threadIdx.x & 63;
    float s = g1[(size_t)n * HID + l] * W_g2[l];
    if (l < HID - 64) s += g1[(size_t)n * HID + 64 + l] * W_g2[64 + l];
    #pragma unroll
    for (int off = 32; off > 0; off >>= 1) s += __shfl_xor(s, off, 64);
    if (l == 0) {
        float gt = s + b_g2[0];
        gate[n] = gt;
        unsigned u = __float_as_uint(gt);
        u = (u & 0x80000000u) ? ~u : (u | 0x80000000u);
        atomicMax(&gmax[batch[n]], u);
    }
}

__global__ void softmax_w(const int* __restrict__ batch, const unsigned* __restrict__ gmax,
                          float* __restrict__ gate, float* __restrict__ wsum)
{
    int n = blockIdx.x * 256 + threadIdx.x;
    if (n >= N_NODES) return;
    unsigned u = gmax[batch[n]];
    float gm = (u & 0x80000000u) ? __uint_as_float(u ^ 0x80000000u) : __uint_as_float(~u);
    float w = expf(gate[n] - gm);
    gate[n] = w;
    atomicAdd(&wsum[batch[n]], w);
}

__global__ void pooled_k(const int* __restrict__ batch, const float* __restrict__ gate,
                         const float* __restrict__ wsum, const float* __restrict__ h,
                         float* __restrict__ pooled)
{
    int idx = blockIdx.x * 256 + threadIdx.x;
    if (idx >= N_NODES * HID) return;
    int n = idx / HID, j = idx - n * HID;
    int b = batch[n];
    float alpha = gate[n] / wsum[b];
    atomicAdd(&pooled[(size_t)b * HID + j], alpha * h[idx]);
}

extern "C" void kernel_launch(void* const* d_in, const int* in_sizes, int n_in,
                              void* d_out, int out_size, void* d_ws, size_t ws_size,
                              hipStream_t stream)
{
    const float* price    = (const float*)d_in[0];
    const int*   cat      = (const int*)d_in[1];
    const int*   sub      = (const int*)d_in[2];
    const int*   elem     = (const int*)d_in[3];
    const int*   brand    = (const int*)d_in[4];
    const int*   pid      = (const int*)d_in[5];
    const int*   eidx     = (const int*)d_in[6];
    const int*   batch    = (const int*)d_in[7];
    const float* emb_cat  = (const float*)d_in[8];
    const float* emb_sub  = (const float*)d_in[9];
    const float* emb_elem = (const float*)d_in[10];
    const float* emb_brand= (const float*)d_in[11];
    const float* emb_item = (const float*)d_in[12];
    const float* W_msg    = (const float*)d_in[13];
    const float* b_msg    = (const float*)d_in[14];
    const float* W_ih     = (const float*)d_in[15];
    const float* W_hh     = (const float*)d_in[16];
    const float* b_ih     = (const float*)d_in[17];
    const float* b_hh     = (const float*)d_in[18];
    const float* W_last   = (const float*)d_in[19];
    const float* b_last   = (const float*)d_in[20];
    const float* W_g1     = (const float*)d_in[21];
    const float* b_g1     = (const float*)d_in[22];
    const float* W_g2     = (const float*)d_in[23];
    const float* b_g2     = (const float*)d_in[24];
    const float* W_fc     = (const float*)d_in[25];
    const float* b_fc     = (const float*)d_in[26];
    float* out = (float*)d_out;

    const int* src = eidx;
    const int* dst = eidx + N_EDGES;

    // ---- workspace layout (float offsets); zeroed region first ----
    float* w = (float*)d_ws;
    float*    msg    = w + 0;          // N*HID        = 4096000
    float*    deg    = w + 4096000;    // N            = 40960
    float*    wsum   = w + 4136960;    // S            = 4096
    float*    pooled = w + 4141056;    // S*HID        = 409600
    int*      lastix = (int*)(w + 4550656);      // S  = 4096
    unsigned* gmax   = (unsigned*)(w + 4554752); // S  = 4096
    // zero region total: 4558848 floats
    float*    Pm     = w + 4558848;    // 57424*HID    = 5742400
    float*    h0     = w + 10301248;   // N*HID        = 4096000
    float*    gi     = w + 14397248;   // region       = 3072000
    float*    gh     = w + 17469248;   // region       = 3072000
    float*    last   = w + 20541248;   // S*HID        = 409600
    float*    gate   = w + 20950848;   // N            = 40960
    // total: 20991808 floats = ~84 MB

    // bf16 hi/lo tables reuse freed regions (all non-overlapping in time):
    unsigned short* MsgH = (unsigned short*)gi;               // [40960][128] = 2621440 fl
    unsigned short* MsgL = (unsigned short*)gh;               // [40960][128]
    unsigned short* Wtab = (unsigned short*)(gh + 2621440);   // 4*38912 sh = 77824 fl
    unsigned short* H0H  = (unsigned short*)Pm;               // [40960][128]
    unsigned short* H0L  = (unsigned short*)(Pm + 2621440);   // ends 5242880 < 5742400
    unsigned short* Bth  = (unsigned short*)msg;              // 3203072 fl < 4096000
    unsigned short* Btl  = (unsigned short*)gi;               // spills into gh (dead)
    unsigned short* Ahp  = (unsigned short*)Pm;               // reused after gru_fused
    unsigned short* Alp  = (unsigned short*)(Pm + 262144);

    hipMemsetAsync(w, 0, (size_t)4558848 * sizeof(float), stream);

    dim3 blk(256);
    auto gemm = [&](const float* A, int lda, const float* B, int ldb,
                    const float* bias, float* C, int ldc, int M, int N, int K, int relu) {
        dim3 g((N + 63) / 64, (M + 63) / 64);
        hipLaunchKernelGGL(gemm_f32, g, blk, 0, stream, A, lda, B, ldb, bias, C, ldc, M, N, K, relu);
    };

    // ---- projected embedding tables for W_msg (row 0 = price handled in gather) ----
    gemm(emb_cat,   DIM, W_msg +   1 * HID, HID, nullptr, Pm +      0, HID,   256, HID, DIM, 0);
    gemm(emb_sub,   DIM, W_msg +  65 * HID, HID, nullptr, Pm +  25600, HID,  1024, HID, DIM, 0);
    gemm(emb_elem,  DIM, W_msg + 129 * HID, HID, nullptr, Pm + 128000, HID,  2048, HID, DIM, 0);
    gemm(emb_brand, DIM, W_msg + 193 * HID, HID, nullptr, Pm + 332800, HID,  4096, HID, DIM, 0);
    gemm(emb_item,  DIM, W_msg + 257 * HID, HID, nullptr, Pm + 742400, HID, VITEMS, HID, DIM, 0);

    // ---- h0 = x @ W_msg + b_msg via gathers ----
    h0_gather<<<16000, blk, 0, stream>>>(price, cat, sub, elem, brand, pid, W_msg, b_msg, Pm, h0);

    // ---- degree + mean aggregation ----
    deg_count<<<320, blk, 0, stream>>>(dst, deg);
    inv_deg_k<<<160, blk, 0, stream>>>(deg);
    msg_scatter<<<32000, blk, 0, stream>>>(src, dst, h0, msg);
    msg_scale<<<16000, blk, 0, stream>>>(deg, msg);

    // ---- fused MFMA GRU (replaces 8 vector GEMMs + 4 gate kernels) ----
    split_pad128<<<20480, blk, 0, stream>>>(msg, N_NODES, MsgH, MsgL);
    split_pad128<<<20480, blk, 0, stream>>>(h0,  N_NODES, H0H,  H0L);
    wtab_split<<<304, blk, 0, stream>>>(W_ih, W_hh, Wtab);
    gru_fused<<<1280, blk, 0, stream>>>(MsgH, MsgL, H0H, H0L, Wtab, b_ih, b_hh, h0);

    // ---- last-node projection and broadcast add ----
    last_idx_k<<<160, blk, 0, stream>>>(batch, lastix);
    last_proj<<<1024, blk, 0, stream>>>(lastix, price, cat, sub, elem, brand, pid,
                                        emb_cat, emb_sub, emb_elem, emb_brand, emb_item,
                                        W_last, b_last, last);
    add_last<<<16000, blk, 0, stream>>>(batch, last, h0);

    // ---- attentional aggregation ----
    gemm(h0, HID, W_g1, HID, b_g1, msg /*reuse as gate1*/, HID, N_NODES, HID, HID, 1);
    gate_reduce<<<10240, blk, 0, stream>>>(msg, W_g2, b_g2, batch, gate, gmax);

    // msg (gate1) is dead now -> build W_fc bf16 hi/lo tables in its place
    b_split<<<782, blk, 0, stream>>>(W_fc, Bth, Btl);

    softmax_w<<<160, blk, 0, stream>>>(batch, gmax, gate, wsum);
    pooled_k<<<16000, blk, 0, stream>>>(batch, gate, wsum, h0, pooled);

    // ---- final scoring: bf16x3 MFMA GEMM with B prefetch ----
    split_pad128<<<2048, blk, 0, stream>>>(pooled, N_SESS, Ahp, Alp);
    score_gemm<<<512, blk, 0, stream>>>(Ahp, Alp, Bth, Btl, b_fc, out);
}